// Round 1
// baseline (32.178 us; speedup 1.0000x reference)
//
#include <hip/hip_runtime.h>
#include <hip/hip_cooperative_groups.h>

namespace cg = cooperative_groups;

#define BB 32
#define NN 1024
#define DD 256

// ---------------- fused cooperative kernel ----------------
// 1024 blocks x 256 threads = 4 blocks/CU on 256 CUs (co-resident).
// Each wave holds 16 rows in registers (lane = float4 fragment), so the
// dot pass after the grid sync needs NO second read of x/y.
#define NSLICE 64                 // 2 tensors * 32 batches
#define BPS 16                    // blocks per slice
#define NBLOCKS (NSLICE * BPS)    // 1024
#define RPB 64                    // rows per block
#define RPW 16                    // rows per wave (4 waves/block)

__global__ __launch_bounds__(256, 4)
void fused_kernel(const float* __restrict__ x, const float* __restrict__ y,
                  float* __restrict__ partial,   // [BPS][NSLICE][DD]
                  float* __restrict__ out) {
    const int bid   = blockIdx.x;
    const int slice = bid / BPS;        // t*32 + b
    const int chunk = bid % BPS;
    const int t     = slice >> 5;       // 0 = x rows, 1 = y rows
    const int b     = slice & 31;
    const int lane  = threadIdx.x & 63;
    const int wave  = threadIdx.x >> 6; // 0..3
    const int d     = threadIdx.x;      // 0..255

    const int row0 = chunk * RPB + wave * RPW;
    const float4* srcv = reinterpret_cast<const float4*>(
        (t == 0 ? x : y) + (size_t)b * NN * DD) + (size_t)row0 * (DD / 4) + lane;

    // ---- phase 1: stream 16 rows into registers, column-sum on the way ----
    float4 v[RPW];
    float4 p = make_float4(0.f, 0.f, 0.f, 0.f);
    #pragma unroll
    for (int r = 0; r < RPW; ++r) {
        v[r] = srcv[(size_t)r * (DD / 4)];
        p.x += v[r].x; p.y += v[r].y; p.z += v[r].z; p.w += v[r].w;
    }

    __shared__ float lds[4][DD];        // 4 KB -> LDS never limits occupancy
    *reinterpret_cast<float4*>(&lds[wave][lane * 4]) = p;
    __syncthreads();
    float ps = lds[0][d] + lds[1][d] + lds[2][d] + lds[3][d];
    partial[((size_t)chunk * NSLICE + slice) * DD + d] = ps;

    __threadfence();                    // device-scope release of partials
    cg::this_grid().sync();             // all partials visible after this

    // ---- phase 2: finish opposite-tensor sum, dot register-held rows ----
    const int opp = slice ^ 32;         // flip tensor, same batch
    const float* pp = partial + (size_t)opp * DD + d;
    float s = 0.f;
    #pragma unroll
    for (int k = 0; k < BPS; ++k) s += pp[(size_t)k * NSLICE * DD];
    lds[0][d] = s;                      // safe: all phase-1 lds reads done
    __syncthreads();

    const float4 sv = *reinterpret_cast<const float4*>(&lds[0][lane * 4]);

    // t==0 (x rows): colsum -> out[b][1024+n]; t==1 (y rows): rowsum -> out[b][m]
    float* outp = out + (size_t)b * 2048 + (t == 0 ? 1024 : 0) + row0;
    #pragma unroll
    for (int r = 0; r < RPW; ++r) {
        float dv = v[r].x * sv.x + v[r].y * sv.y + v[r].z * sv.z + v[r].w * sv.w;
        #pragma unroll
        for (int off = 32; off >= 1; off >>= 1)
            dv += __shfl_down(dv, off, 64);
        if (lane == 0) outp[r] = dv;
    }
}

// ---------------- fallback: previous two-kernel path ----------------
#define SPLIT 8
#define CHUNK (NN / SPLIT)

__global__ void colsum_partial_kernel(const float* __restrict__ x,
                                      const float* __restrict__ y,
                                      float* __restrict__ partial) {
    int bid = blockIdx.x;
    int t   = bid / (BB * SPLIT);
    int rem = bid % (BB * SPLIT);
    int b   = rem / SPLIT;
    int s   = rem % SPLIT;
    int d   = threadIdx.x;

    const float* src = (t == 0 ? x : y)
                     + (size_t)b * NN * DD + (size_t)s * CHUNK * DD + d;

    float a0 = 0.f, a1 = 0.f, a2 = 0.f, a3 = 0.f;
    #pragma unroll 4
    for (int n = 0; n < CHUNK; n += 4) {
        a0 += src[(size_t)(n + 0) * DD];
        a1 += src[(size_t)(n + 1) * DD];
        a2 += src[(size_t)(n + 2) * DD];
        a3 += src[(size_t)(n + 3) * DD];
    }
    partial[(((size_t)t * SPLIT + s) * BB + b) * DD + d] = (a0 + a1) + (a2 + a3);
}

#define RCHUNKS 16
#define ROWS_PER_BLOCK 64

__global__ void dots_kernel(const float* __restrict__ x,
                            const float* __restrict__ y,
                            const float* __restrict__ partial,
                            float* __restrict__ out) {
    int bid = blockIdx.x;
    int rc  = bid % RCHUNKS;
    int bt  = bid / RCHUNKS;
    int t   = bt & 1;
    int b   = bt >> 1;
    int d   = threadIdx.x;

    __shared__ float ssum[DD];
    {
        const float* p = partial + ((size_t)t * SPLIT * BB + b) * DD + d;
        float s = 0.f;
        #pragma unroll
        for (int k = 0; k < SPLIT; ++k) s += p[(size_t)k * BB * DD];
        ssum[d] = s;
    }
    __syncthreads();

    int lane = threadIdx.x & 63;
    int wave = threadIdx.x >> 6;

    float4 sv = *reinterpret_cast<const float4*>(&ssum[lane * 4]);
    const float* data = (t == 0 ? y : x) + (size_t)b * NN * DD;
    float* outp = out + (size_t)b * 2048 + (size_t)t * 1024;

    int r0 = rc * ROWS_PER_BLOCK + wave * 16;
    #pragma unroll 4
    for (int r = 0; r < 16; ++r) {
        int row = r0 + r;
        float4 w = *reinterpret_cast<const float4*>(&data[(size_t)row * DD + lane * 4]);
        float dotv = w.x * sv.x + w.y * sv.y + w.z * sv.z + w.w * sv.w;
        #pragma unroll
        for (int off = 32; off >= 1; off >>= 1)
            dotv += __shfl_down(dotv, off, 64);
        if (lane == 0) outp[row] = dotv;
    }
}

extern "C" void kernel_launch(void* const* d_in, const int* in_sizes, int n_in,
                              void* d_out, int out_size, void* d_ws, size_t ws_size,
                              hipStream_t stream) {
    const float* x = (const float*)d_in[0];
    const float* y = (const float*)d_in[1];
    float* out     = (float*)d_out;
    float* partial = (float*)d_ws;     // fused: 1 MB; fallback: 512 KB

    static int use_coop = -1;
    if (use_coop < 0) {
        int nb = 0;
        hipError_t e = hipOccupancyMaxActiveBlocksPerMultiprocessor(
            &nb, (const void*)fused_kernel, 256, 0);
        use_coop = (e == hipSuccess && nb >= 4) ? 1 : 0;   // need 4 blocks/CU
    }

    if (use_coop) {
        void* args[] = { (void*)&x, (void*)&y, (void*)&partial, (void*)&out };
        hipError_t e = hipLaunchCooperativeKernel(
            (const void*)fused_kernel, dim3(NBLOCKS), dim3(256), args, 0, stream);
        if (e == hipSuccess) return;
        use_coop = 0;                   // cooperative path unavailable: fall back
    }

    colsum_partial_kernel<<<2 * BB * SPLIT, 256, 0, stream>>>(x, y, partial);
    dots_kernel<<<BB * 2 * RCHUNKS, 256, 0, stream>>>(x, y, partial, out);
}

// Round 2
// 27.287 us; speedup vs baseline: 1.1792x; 1.1792x over previous
//
#include <hip/hip_runtime.h>
#include <hip/hip_cooperative_groups.h>

namespace cg = cooperative_groups;

#define BB 32
#define NN 1024
#define DD 256

// ---------------- fused cooperative kernel ----------------
// 1024 blocks x 256 threads = 4 blocks/CU on 256 CUs (co-resident).
// Each wave holds 16 rows in registers (lane = float4 fragment); an opaque
// asm touch pins them in VGPRs so the post-sync dot pass re-reads NOTHING.
#define NSLICE 64                 // 2 tensors * 32 batches
#define BPS 16                    // blocks per slice
#define NBLOCKS (NSLICE * BPS)    // 1024
#define RPB 64                    // rows per block
#define RPW 16                    // rows per wave (4 waves/block)

__global__ __launch_bounds__(256, 4)
void fused_kernel(const float* __restrict__ x, const float* __restrict__ y,
                  float* __restrict__ partial,   // [BPS][NSLICE][DD]
                  float* __restrict__ out) {
    const int bid   = blockIdx.x;
    const int slice = bid / BPS;        // t*32 + b
    const int chunk = bid % BPS;
    const int t     = slice >> 5;       // 0 = x rows, 1 = y rows
    const int b     = slice & 31;
    const int lane  = threadIdx.x & 63;
    const int wave  = threadIdx.x >> 6; // 0..3
    const int d     = threadIdx.x;      // 0..255

    const int row0 = chunk * RPB + wave * RPW;
    const float4* srcv = reinterpret_cast<const float4*>(
        (t == 0 ? x : y) + (size_t)b * NN * DD) + (size_t)row0 * (DD / 4) + lane;

    // ---- phase 1: stream 16 rows into registers, column-sum on the way ----
    float4 v[RPW];
    float4 p = make_float4(0.f, 0.f, 0.f, 0.f);
    #pragma unroll
    for (int r = 0; r < RPW; ++r) {
        v[r] = srcv[(size_t)r * (DD / 4)];
        p.x += v[r].x; p.y += v[r].y; p.z += v[r].z; p.w += v[r].w;
    }

    // Pin the 16 rows in VGPRs: "+v" makes each value's origin opaque, so the
    // compiler cannot rematerialize the global loads after the grid sync.
    // (Round-1 failure mode: VGPR_Count=48 -> rows were re-loaded in phase 2.)
    #pragma unroll
    for (int r = 0; r < RPW; ++r) {
        asm volatile("" : "+v"(v[r].x), "+v"(v[r].y), "+v"(v[r].z), "+v"(v[r].w));
    }

    __shared__ float lds[4][DD];        // 4 KB -> LDS never limits occupancy
    *reinterpret_cast<float4*>(&lds[wave][lane * 4]) = p;
    __syncthreads();
    float ps = lds[0][d] + lds[1][d] + lds[2][d] + lds[3][d];
    partial[((size_t)chunk * NSLICE + slice) * DD + d] = ps;

    __threadfence();                    // device-scope release of partials
    cg::this_grid().sync();             // all partials visible after this

    // ---- phase 2: finish opposite-tensor sum, dot register-held rows ----
    const int opp = slice ^ 32;         // flip tensor, same batch
    const float* pp = partial + (size_t)opp * DD + d;
    float s = 0.f;
    #pragma unroll
    for (int k = 0; k < BPS; ++k) s += pp[(size_t)k * NSLICE * DD];
    lds[0][d] = s;                      // safe: all phase-1 lds reads done
    __syncthreads();

    const float4 sv = *reinterpret_cast<const float4*>(&lds[0][lane * 4]);

    // t==0 (x rows): colsum -> out[b][1024+n]; t==1 (y rows): rowsum -> out[b][m]
    float* outp = out + (size_t)b * 2048 + (t == 0 ? 1024 : 0) + row0;
    #pragma unroll
    for (int r = 0; r < RPW; ++r) {
        float dv = v[r].x * sv.x + v[r].y * sv.y + v[r].z * sv.z + v[r].w * sv.w;
        #pragma unroll
        for (int off = 32; off >= 1; off >>= 1)
            dv += __shfl_down(dv, off, 64);
        if (lane == 0) outp[r] = dv;
    }
}

// ---------------- fallback: previous two-kernel path ----------------
#define SPLIT 8
#define CHUNK (NN / SPLIT)

__global__ void colsum_partial_kernel(const float* __restrict__ x,
                                      const float* __restrict__ y,
                                      float* __restrict__ partial) {
    int bid = blockIdx.x;
    int t   = bid / (BB * SPLIT);
    int rem = bid % (BB * SPLIT);
    int b   = rem / SPLIT;
    int s   = rem % SPLIT;
    int d   = threadIdx.x;

    const float* src = (t == 0 ? x : y)
                     + (size_t)b * NN * DD + (size_t)s * CHUNK * DD + d;

    float a0 = 0.f, a1 = 0.f, a2 = 0.f, a3 = 0.f;
    #pragma unroll 4
    for (int n = 0; n < CHUNK; n += 4) {
        a0 += src[(size_t)(n + 0) * DD];
        a1 += src[(size_t)(n + 1) * DD];
        a2 += src[(size_t)(n + 2) * DD];
        a3 += src[(size_t)(n + 3) * DD];
    }
    partial[(((size_t)t * SPLIT + s) * BB + b) * DD + d] = (a0 + a1) + (a2 + a3);
}

#define RCHUNKS 16
#define ROWS_PER_BLOCK 64

__global__ void dots_kernel(const float* __restrict__ x,
                            const float* __restrict__ y,
                            const float* __restrict__ partial,
                            float* __restrict__ out) {
    int bid = blockIdx.x;
    int rc  = bid % RCHUNKS;
    int bt  = bid / RCHUNKS;
    int t   = bt & 1;
    int b   = bt >> 1;
    int d   = threadIdx.x;

    __shared__ float ssum[DD];
    {
        const float* p = partial + ((size_t)t * SPLIT * BB + b) * DD + d;
        float s = 0.f;
        #pragma unroll
        for (int k = 0; k < SPLIT; ++k) s += p[(size_t)k * BB * DD];
        ssum[d] = s;
    }
    __syncthreads();

    int lane = threadIdx.x & 63;
    int wave = threadIdx.x >> 6;

    float4 sv = *reinterpret_cast<const float4*>(&ssum[lane * 4]);
    const float* data = (t == 0 ? y : x) + (size_t)b * NN * DD;
    float* outp = out + (size_t)b * 2048 + (size_t)t * 1024;

    int r0 = rc * ROWS_PER_BLOCK + wave * 16;
    #pragma unroll 4
    for (int r = 0; r < 16; ++r) {
        int row = r0 + r;
        float4 w = *reinterpret_cast<const float4*>(&data[(size_t)row * DD + lane * 4]);
        float dotv = w.x * sv.x + w.y * sv.y + w.z * sv.z + w.w * sv.w;
        #pragma unroll
        for (int off = 32; off >= 1; off >>= 1)
            dotv += __shfl_down(dotv, off, 64);
        if (lane == 0) outp[row] = dotv;
    }
}

extern "C" void kernel_launch(void* const* d_in, const int* in_sizes, int n_in,
                              void* d_out, int out_size, void* d_ws, size_t ws_size,
                              hipStream_t stream) {
    const float* x = (const float*)d_in[0];
    const float* y = (const float*)d_in[1];
    float* out     = (float*)d_out;
    float* partial = (float*)d_ws;     // fused: 1 MB; fallback: 512 KB

    static int use_coop = -1;
    if (use_coop < 0) {
        int nb = 0;
        hipError_t e = hipOccupancyMaxActiveBlocksPerMultiprocessor(
            &nb, (const void*)fused_kernel, 256, 0);
        use_coop = (e == hipSuccess && nb >= 4) ? 1 : 0;   // need 4 blocks/CU
    }

    if (use_coop) {
        void* args[] = { (void*)&x, (void*)&y, (void*)&partial, (void*)&out };
        hipError_t e = hipLaunchCooperativeKernel(
            (const void*)fused_kernel, dim3(NBLOCKS), dim3(256), args, 0, stream);
        if (e == hipSuccess) return;
        use_coop = 0;                   // cooperative path unavailable: fall back
    }

    colsum_partial_kernel<<<2 * BB * SPLIT, 256, 0, stream>>>(x, y, partial);
    dots_kernel<<<BB * 2 * RCHUNKS, 256, 0, stream>>>(x, y, partial, out);
}